// Round 2
// baseline (1550.696 us; speedup 1.0000x reference)
//
#include <hip/hip_runtime.h>
#include <hip/hip_bf16.h>
#include <cstdint>

#define NNODES 50000
#define NEDGES 800000
#define NGRAPHS 50
#define NPG 1000
#define NB_SCAN 196   // ceil(50000/256)

// consts layout (floats) in ws[0..1023]
#define CO_WEAE 0
#define CO_WEC2 16
#define CO_BES  18
#define CO_EMBS 20
#define CO_WS   48
#define CO_WD   128
#define CO_BN1S 208
#define CO_BN1SH 288
#define CO_BN2S 368
#define CO_BN2SH 448
#define CO_BN3S 528
#define CO_BN3SH 608

__device__ __forceinline__ float lrelu(float x){ return x >= 0.f ? x : 0.2f*x; }
__device__ __forceinline__ float siluf(float x){ return x / (1.f + __expf(-x)); }

__device__ __forceinline__ int wave_incl_scan(int v) {
    int lane = threadIdx.x & 63;
    #pragma unroll
    for (int d = 1; d < 64; d <<= 1) {
        int o = __shfl_up(v, d, 64);
        if (lane >= d) v += o;
    }
    return v;
}

// ---------------- precompute folded constants ----------------
__global__ __launch_bounds__(256) void k_precompute(
        const float* __restrict__ gat_W, const float* __restrict__ gat_as, const float* __restrict__ gat_ad,
        const float* __restrict__ gat_We, const float* __restrict__ gat_ae,
        const float* __restrict__ W_edge, const float* __restrict__ b_edge, const float* __restrict__ edge_emb,
        const float* __restrict__ bn1_w, const float* __restrict__ bn1_b, const float* __restrict__ bn1_m, const float* __restrict__ bn1_v,
        const float* __restrict__ bn2_w, const float* __restrict__ bn2_b, const float* __restrict__ bn2_m, const float* __restrict__ bn2_v,
        const float* __restrict__ bn3_w, const float* __restrict__ bn3_b, const float* __restrict__ bn3_m, const float* __restrict__ bn3_v,
        float* __restrict__ consts)
{
    __shared__ float weae[16];
    int tid = threadIdx.x;
    if (tid < 16) {
        float s = 0.f;
        for (int c = 0; c < 80; ++c) s += gat_We[tid*80 + c] * gat_ae[c];
        weae[tid] = s;
        consts[CO_WEAE + tid] = s;
    }
    __syncthreads();
    if (tid < 2) {
        float s = 0.f;
        for (int k = 0; k < 16; ++k) s += W_edge[tid*16 + k] * weae[k];
        consts[CO_WEC2 + tid] = s;
    } else if (tid == 2) {
        float s = 0.f;
        for (int k = 0; k < 16; ++k) s += b_edge[k] * weae[k];
        consts[CO_BES] = s;
    }
    if (tid >= 32 && tid < 53) {
        int j = tid - 32;
        float s = 0.f;
        for (int k = 0; k < 16; ++k) s += edge_emb[j*16 + k] * weae[k];
        consts[CO_EMBS + j] = s;
    }
    if (tid >= 64 && tid < 144) {
        int r = tid - 64;
        float s1 = 0.f, s2 = 0.f;
        for (int c = 0; c < 80; ++c) {
            float w = gat_W[r*80 + c];
            s1 += w * gat_as[c];
            s2 += w * gat_ad[c];
        }
        consts[CO_WS + r] = s1;
        consts[CO_WD + r] = s2;
    }
    if (tid >= 160 && tid < 240) {
        int c = tid - 160;
        float sc1 = bn1_w[c] / sqrtf(bn1_v[c] + 1e-5f);
        consts[CO_BN1S + c] = sc1; consts[CO_BN1SH + c] = bn1_b[c] - bn1_m[c]*sc1;
        float sc2 = bn2_w[c] / sqrtf(bn2_v[c] + 1e-5f);
        consts[CO_BN2S + c] = sc2; consts[CO_BN2SH + c] = bn2_b[c] - bn2_m[c]*sc2;
        float sc3 = bn3_w[c] / sqrtf(bn3_v[c] + 1e-5f);
        consts[CO_BN3S + c] = sc3; consts[CO_BN3SH + c] = bn3_b[c] - bn3_m[c]*sc3;
    }
}

// ---------------- node features: xf = x[:,2:1026]@W_uni + b_uni ; pe ----------------
__global__ __launch_bounds__(256) void k_feat(const float* __restrict__ x,
        const float* __restrict__ W, const float* __restrict__ b,
        float* __restrict__ h)
{
    __shared__ float As[32][68];   // [k][row], padded
    __shared__ float Bs[32][64];   // [k][col]
    int tid = threadIdx.x;
    int node0 = blockIdx.x * 64;
    int tx = tid & 15, ty = tid >> 4;
    float acc[4][4] = {};
    int lr = tid >> 2;            // A-load row 0..63
    int lk = (tid & 3) * 8;       // A-load k base
    int bk = tid >> 3;            // B-load k 0..31
    int bc = (tid & 7) * 8;       // B-load col base
    for (int kk = 0; kk < 1024; kk += 32) {
        int n = node0 + lr;
        if (n < NNODES) {
            const float* xp = x + (size_t)n*1026 + 2 + kk + lk;
            #pragma unroll
            for (int j = 0; j < 8; ++j) As[lk+j][lr] = xp[j];
        } else {
            #pragma unroll
            for (int j = 0; j < 8; ++j) As[lk+j][lr] = 0.f;
        }
        const float* wp = W + (size_t)(kk+bk)*64 + bc;
        #pragma unroll
        for (int j = 0; j < 8; ++j) Bs[bk][bc+j] = wp[j];
        __syncthreads();
        #pragma unroll 8
        for (int i = 0; i < 32; ++i) {
            const float4 a  = *(const float4*)&As[i][ty*4];
            const float4 bb = *(const float4*)&Bs[i][tx*4];
            float av[4] = {a.x, a.y, a.z, a.w};
            float bv[4] = {bb.x, bb.y, bb.z, bb.w};
            #pragma unroll
            for (int r = 0; r < 4; ++r)
                #pragma unroll
                for (int j = 0; j < 4; ++j)
                    acc[r][j] = fmaf(av[r], bv[j], acc[r][j]);
        }
        __syncthreads();
    }
    #pragma unroll
    for (int r = 0; r < 4; ++r) {
        int n = node0 + ty*4 + r;
        if (n < NNODES) {
            #pragma unroll
            for (int j = 0; j < 4; ++j) {
                int c = tx*4 + j;
                h[(size_t)n*80 + c] = acc[r][j] + b[c];
            }
        }
    }
    // positional encoding: cols 64..79
    for (int idx = tid; idx < 64*16; idx += 256) {
        int row = idx >> 4, col = idx & 15;
        int n = node0 + row;
        if (n < NNODES) {
            float pos = x[(size_t)n*1026 + (col < 8 ? 0 : 1)];
            int jj = (col & 7) >> 1;
            const float dens[4] = {1.f, 10.f, 100.f, 1000.f};
            float ang = pos / dens[jj];
            float v = (col & 1) ? cosf(ang) : sinf(ang);
            h[(size_t)n*80 + 64 + col] = v;
        }
    }
}

// ---------------- generic row-GEMM: out[n,c] = sum_k in[n,k] W[k,c] (+epilogue) ----------------
template<int K, int C, int RPT, int EPI>
__global__ __launch_bounds__(320) void k_gemm_rows(const float* __restrict__ in,
        const float* __restrict__ W, float* __restrict__ out, float* __restrict__ out2,
        const float* __restrict__ extra, const float* __restrict__ consts, int N)
{
    constexpr int GROUPS = 320 / C;
    constexpr int NPB = GROUPS * RPT;
    __shared__ float rows[NPB][K];
    int tid = threadIdx.x;
    int n0 = blockIdx.x * NPB;
    for (int idx = tid; idx < NPB*K; idx += 320) {
        int r = idx / K, k = idx - r*K;
        int n = n0 + r;
        rows[r][k] = (n < N) ? in[(size_t)n*K + k] : 0.f;
    }
    __syncthreads();
    int c = tid % C, grp = tid / C;
    float acc[RPT];
    #pragma unroll
    for (int r = 0; r < RPT; ++r) acc[r] = 0.f;
    #pragma unroll 4
    for (int k = 0; k < K; ++k) {
        float w = W[(size_t)k*C + c];
        #pragma unroll
        for (int r = 0; r < RPT; ++r) acc[r] = fmaf(rows[grp*RPT + r][k], w, acc[r]);
    }
    #pragma unroll
    for (int r = 0; r < RPT; ++r) {
        int n = n0 + grp*RPT + r;
        if (n >= N) continue;
        float v = acc[r];
        if (EPI == 0) {
            out[(size_t)n*C + c] = v;
        } else if (EPI == 1) {          // xz: cols<80 -> xc, cols>=80 -> silu(z)
            if (c < 80) out[(size_t)n*80 + c] = v;
            else        out2[(size_t)n*80 + (c-80)] = siluf(v);
        } else if (EPI == 2) {          // bn2 + add hgbn -> s1
            float bv = consts[CO_BN2S + c]*v + consts[CO_BN2SH + c] + extra[(size_t)n*80 + c];
            out[(size_t)n*80 + c] = bv;
        }
    }
}

// ---------------- per-edge scalar attention term + per-dst sums ----------------
__global__ __launch_bounds__(256) void k_edge_scalar(const float* __restrict__ ea_cont,
        const int* __restrict__ ea_cat, const int* __restrict__ dst,
        const float* __restrict__ consts, float* __restrict__ a_e,
        float* __restrict__ sum_ae, int* __restrict__ cnt)
{
    int e = blockIdx.x * 256 + threadIdx.x;
    if (e >= NEDGES) return;
    float2 ec = ((const float2*)ea_cont)[e];
    float v = ec.x*consts[CO_WEC2] + ec.y*consts[CO_WEC2+1] + consts[CO_BES]
            + consts[CO_EMBS + ea_cat[e]];
    a_e[e] = v;
    int d = dst[e];
    atomicAdd(sum_ae + d, v);
    atomicAdd(cnt + d, 1);
}

// ---------------- per-node: a_s, a_d, self-loop alpha ----------------
__global__ __launch_bounds__(256) void k_node_as(const float* __restrict__ h,
        const float* __restrict__ consts, const float* __restrict__ sum_ae,
        const int* __restrict__ cnt, float* __restrict__ a_s, float* __restrict__ a_d,
        float* __restrict__ alpha_self)
{
    __shared__ float wsv[80], wdv[80];
    int tid = threadIdx.x;
    if (tid < 80) { wsv[tid] = consts[CO_WS + tid]; wdv[tid] = consts[CO_WD + tid]; }
    __syncthreads();
    int n = blockIdx.x * 256 + tid;
    if (n >= NNODES) return;
    const float4* hr = (const float4*)(h + (size_t)n*80);
    float as = 0.f, ad = 0.f;
    #pragma unroll 5
    for (int i = 0; i < 20; ++i) {
        float4 f = hr[i];
        as += f.x*wsv[i*4] + f.y*wsv[i*4+1] + f.z*wsv[i*4+2] + f.w*wsv[i*4+3];
        ad += f.x*wdv[i*4] + f.y*wdv[i*4+1] + f.z*wdv[i*4+2] + f.w*wdv[i*4+3];
    }
    float aes = sum_ae[n] / fmaxf((float)cnt[n], 1.f);
    a_s[n] = as; a_d[n] = ad;
    alpha_self[n] = lrelu(as + ad + aes);
}

// ---------------- exclusive scan of cnt -> rowptr (3 kernels) ----------------
__global__ __launch_bounds__(256) void k_psum1(const int* __restrict__ cnt, int* __restrict__ bsum)
{
    __shared__ int ws4[4];
    int tid = threadIdx.x;
    int n = blockIdx.x*256 + tid;
    int v = (n < NNODES) ? cnt[n] : 0;
    int s = wave_incl_scan(v);
    if ((tid & 63) == 63) ws4[tid >> 6] = s;
    __syncthreads();
    if (tid == 0) {
        int t = 0;
        for (int w = 0; w < 4; ++w) t += ws4[w];
        bsum[blockIdx.x] = t;
    }
}

__global__ __launch_bounds__(256) void k_psum2(int* __restrict__ bsum)
{
    __shared__ int wsum[4], woff[4];
    int tid = threadIdx.x;
    int v = (tid < NB_SCAN) ? bsum[tid] : 0;
    int s = wave_incl_scan(v);
    if ((tid & 63) == 63) wsum[tid >> 6] = s;
    __syncthreads();
    if (tid == 0) { int r = 0; for (int w = 0; w < 4; ++w) { woff[w] = r; r += wsum[w]; } }
    __syncthreads();
    int excl = s - v + woff[tid >> 6];
    if (tid < NB_SCAN) bsum[tid] = excl;
}

__global__ __launch_bounds__(256) void k_psum3(const int* __restrict__ cnt,
        const int* __restrict__ bsum, int* __restrict__ rowptr, int* __restrict__ cursor)
{
    __shared__ int wsum[4], woff[4];
    int tid = threadIdx.x;
    int n = blockIdx.x*256 + tid;
    int v = (n < NNODES) ? cnt[n] : 0;
    int s = wave_incl_scan(v);
    if ((tid & 63) == 63) wsum[tid >> 6] = s;
    __syncthreads();
    if (tid == 0) { int r = 0; for (int w = 0; w < 4; ++w) { woff[w] = r; r += wsum[w]; } }
    __syncthreads();
    int excl = s - v + woff[tid >> 6] + bsum[blockIdx.x];
    if (n < NNODES) { rowptr[n] = excl; cursor[n] = excl; }
}

// ---------------- bucket fill: (src, alpha) grouped by dst ----------------
__global__ __launch_bounds__(256) void k_bucket(const int* __restrict__ src,
        const int* __restrict__ dst, const float* __restrict__ a_s,
        const float* __restrict__ a_d, const float* __restrict__ a_e,
        int* __restrict__ cursor, int2* __restrict__ ebuf)
{
    int e = blockIdx.x*256 + threadIdx.x;
    if (e >= NEDGES) return;
    int sN = src[e], d = dst[e];
    float al = lrelu(a_s[sN] + a_d[d] + a_e[e]);
    int pos = atomicAdd(cursor + d, 1);
    ebuf[pos] = make_int2(sN, __float_as_int(al));
}

// ---------------- GAT aggregate (CSR gather): 16 lanes/node ----------------
__global__ __launch_bounds__(256) void k_gat_agg(const int* __restrict__ rowptr,
        const int* __restrict__ cnt, const int2* __restrict__ ebuf,
        const float* __restrict__ alpha_self, const float* __restrict__ hg,
        const float* __restrict__ gat_b, const float* __restrict__ consts,
        float* __restrict__ hgbn)
{
    int tid = threadIdx.x;
    int grp = tid >> 4, l = tid & 15;
    int n = blockIdx.x*16 + grp;
    if (n >= NNODES) return;
    int r0 = rowptr[n], c = cnt[n];
    float aself = alpha_self[n];
    // pass 1: max over edge alphas (lane-strided) + self
    float m = aself;
    for (int i = l; i < c; i += 16)
        m = fmaxf(m, __int_as_float(ebuf[r0 + i].y));
    m = fmaxf(m, __shfl_xor(m, 1, 16));
    m = fmaxf(m, __shfl_xor(m, 2, 16));
    m = fmaxf(m, __shfl_xor(m, 4, 16));
    m = fmaxf(m, __shfl_xor(m, 8, 16));
    // pass 2: softmax-weighted gather; lane l owns channels l+16j
    float ex0 = __expf(aself - m);
    float denom = ex0;
    float acc[5];
    const float* hn = hg + (size_t)n*80;
    #pragma unroll
    for (int j = 0; j < 5; ++j) acc[j] = ex0 * hn[l + 16*j];
    for (int i = 0; i < c; ++i) {
        int2 p = ebuf[r0 + i];
        float ex = __expf(__int_as_float(p.y) - m);
        denom += ex;
        const float* hs = hg + (size_t)p.x*80;
        #pragma unroll
        for (int j = 0; j < 5; ++j) acc[j] = fmaf(ex, hs[l + 16*j], acc[j]);
    }
    float inv = 1.f/denom;
    #pragma unroll
    for (int j = 0; j < 5; ++j) {
        int ch = l + 16*j;
        float v = acc[j]*inv + gat_b[ch];
        hgbn[(size_t)n*80 + ch] = consts[CO_BN1S + ch]*v + consts[CO_BN1SH + ch];
    }
}

// ---------------- mamba: depthwise conv + silu, x_proj, dt ----------------
__global__ __launch_bounds__(256) void k_conv_proj(const float* __restrict__ xc,
        const float* __restrict__ conv_w, const float* __restrict__ conv_b,
        const float* __restrict__ xp_W, const float* __restrict__ dt_W,
        const float* __restrict__ dt_b, float* __restrict__ u_g,
        float* __restrict__ Bm, float* __restrict__ Cm, float* __restrict__ dt_g)
{
    __shared__ float us[40][80];
    __shared__ float dtr[40][5];
    int g = blockIdx.x / 25, chunk = blockIdx.x % 25;
    int t0 = chunk * 40;
    int tid = threadIdx.x;
    size_t gbase = (size_t)g * NPG;
    for (int idx = tid; idx < 40*80; idx += 256) {
        int t = idx / 80, d = idx - t*80;
        int tt = t0 + t;
        float acc = conv_b[d];
        #pragma unroll
        for (int k = 0; k < 4; ++k) {
            int ti = tt - 3 + k;
            float xv = (ti >= 0) ? xc[(gbase + ti)*80 + d] : 0.f;
            acc = fmaf(xv, conv_w[d*4 + k], acc);
        }
        float uv = siluf(acc);
        us[t][d] = uv;
        u_g[(gbase + tt)*80 + d] = uv;
    }
    __syncthreads();
    for (int idx = tid; idx < 40*37; idx += 256) {
        int t = idx / 37, j = idx - t*37;
        float acc = 0.f;
        #pragma unroll 4
        for (int k = 0; k < 80; ++k) acc = fmaf(us[t][k], xp_W[k*37 + j], acc);
        int tt = t0 + t;
        if (j < 5) dtr[t][j] = acc;
        else if (j < 21) Bm[(gbase + tt)*16 + (j-5)] = acc;
        else Cm[(gbase + tt)*16 + (j-21)] = acc;
    }
    __syncthreads();
    for (int idx = tid; idx < 40*80; idx += 256) {
        int t = idx / 80, d = idx - t*80;
        float acc = dt_b[d];
        #pragma unroll
        for (int r = 0; r < 5; ++r) acc = fmaf(dtr[t][r], dt_W[r*80 + d], acc);
        float sp = (acc > 20.f) ? acc : log1pf(__expf(acc));
        dt_g[(gbase + t0 + t)*80 + d] = sp;
    }
}

// ---------------- SSM scan: thread = (graph, d, s); 16-lane reduce for y ----------------
__global__ __launch_bounds__(256) void k_scan(const float* __restrict__ dt,
        const float* __restrict__ u, const float* __restrict__ Bm,
        const float* __restrict__ Cm, const float* __restrict__ A_log,
        const float* __restrict__ Dp, const float* __restrict__ sz,
        float* __restrict__ yraw)
{
    int g = blockIdx.x / 5, dblk = blockIdx.x % 5;
    int dl = threadIdx.x >> 4, s = threadIdx.x & 15;
    int d = dblk*16 + dl;
    float a = -__expf(A_log[d*16 + s]);
    float Dd = Dp[d];
    size_t base80 = (size_t)g*NPG*80 + d;
    size_t base16 = (size_t)g*NPG*16 + s;
    float hst = 0.f;
    float dtv = dt[base80], uv = u[base80], Bv = Bm[base16], Cv = Cm[base16];
    for (int t = 0; t < NPG; ++t) {
        float ndt = 0.f, nu = 0.f, nB = 0.f, nC = 0.f;
        if (t < NPG-1) {
            size_t i80 = base80 + (size_t)(t+1)*80;
            size_t i16 = base16 + (size_t)(t+1)*16;
            ndt = dt[i80]; nu = u[i80]; nB = Bm[i16]; nC = Cm[i16];
        }
        float dA = __expf(dtv * a);
        hst = fmaf(dA, hst, dtv*uv*Bv);
        float c = hst * Cv;
        c += __shfl_xor(c, 1, 16);
        c += __shfl_xor(c, 2, 16);
        c += __shfl_xor(c, 4, 16);
        c += __shfl_xor(c, 8, 16);
        if (s == 0) {
            size_t i = base80 + (size_t)t*80;
            float yv = c + uv*Dd;
            yraw[i] = yv * sz[i];
        }
        dtv = ndt; uv = nu; Bv = nB; Cv = nC;
    }
}

// ---------------- residual MLP + bn3 + relu + pooled accumulation ----------------
__global__ __launch_bounds__(640) void k_mlp(const float* __restrict__ s1,
        const float* __restrict__ W1, const float* __restrict__ b1,
        const float* __restrict__ W2, const float* __restrict__ b2,
        const float* __restrict__ consts, float* __restrict__ pooled)
{
    __shared__ float s1s[4][80];
    __shared__ float t1s[4][160];
    int tid = threadIdx.x;
    int n0 = blockIdx.x * 4;
    if (tid < 320) {
        int r = tid / 80, c = tid - r*80;
        s1s[r][c] = s1[(size_t)(n0 + r)*80 + c];
    }
    __syncthreads();
    {
        int r = tid / 160, j = tid - (tid/160)*160;
        float acc = b1[j];
        #pragma unroll 4
        for (int k = 0; k < 80; ++k) acc = fmaf(s1s[r][k], W1[k*160 + j], acc);
        t1s[r][j] = fmaxf(acc, 0.f);
    }
    __syncthreads();
    if (tid < 320) {
        int r = tid / 80, c = tid - (tid/80)*80;
        float acc = b2[c];
        #pragma unroll 4
        for (int k = 0; k < 160; ++k) acc = fmaf(t1s[r][k], W2[k*80 + c], acc);
        float v = s1s[r][c] + acc;
        v = consts[CO_BN3S + c]*v + consts[CO_BN3SH + c];
        v = fmaxf(v, 0.f);
        s1s[r][c] = v;
    }
    __syncthreads();
    if (tid < 80) {
        float sum = s1s[0][tid] + s1s[1][tid] + s1s[2][tid] + s1s[3][tid];
        atomicAdd(pooled + (n0 / NPG)*80 + tid, sum);
    }
}

// ---------------- pooled mean + final 3-layer MLP ----------------
__global__ __launch_bounds__(256) void k_pool_final(const float* __restrict__ pooled,
        const float* __restrict__ f_W1, const float* __restrict__ f_b1,
        const float* __restrict__ f_W2, const float* __restrict__ f_b2,
        const float* __restrict__ f_W3, const float* __restrict__ f_b3,
        float* __restrict__ d_out)
{
    __shared__ float pl[50*80];
    __shared__ float h1[50*40];
    __shared__ float h2[50*20];
    int tid = threadIdx.x;
    for (int idx = tid; idx < 50*80; idx += 256) {
        float v = pooled[idx] * (1.f/NPG);
        pl[idx] = v;
        d_out[50 + idx] = v;
    }
    __syncthreads();
    for (int idx = tid; idx < 50*40; idx += 256) {
        int g = idx / 40, j = idx - g*40;
        float acc = f_b1[j];
        for (int k = 0; k < 80; ++k) acc = fmaf(pl[g*80+k], f_W1[k*40+j], acc);
        h1[idx] = fmaxf(acc, 0.f);
    }
    __syncthreads();
    for (int idx = tid; idx < 50*20; idx += 256) {
        int g = idx / 20, j = idx - g*20;
        float acc = f_b2[j];
        for (int k = 0; k < 40; ++k) acc = fmaf(h1[g*40+k], f_W2[k*20+j], acc);
        h2[idx] = fmaxf(acc, 0.f);
    }
    __syncthreads();
    if (tid < 50) {
        float acc = f_b3[0];
        for (int k = 0; k < 20; ++k) acc = fmaf(h2[tid*20+k], f_W3[k], acc);
        d_out[tid] = acc;
    }
}

extern "C" void kernel_launch(void* const* d_in, const int* in_sizes, int n_in,
                              void* d_out, int out_size, void* d_ws, size_t ws_size,
                              hipStream_t stream)
{
    (void)in_sizes; (void)n_in; (void)out_size; (void)ws_size;
    const float* x        = (const float*)d_in[0];
    const int*   eidx     = (const int*)d_in[1];
    const int*   ea_cat   = (const int*)d_in[2];
    const float* ea_cont  = (const float*)d_in[3];
    const float* W_uni    = (const float*)d_in[4];
    const float* b_uni    = (const float*)d_in[5];
    const float* edge_emb = (const float*)d_in[6];
    const float* W_edge   = (const float*)d_in[7];
    const float* b_edge   = (const float*)d_in[8];
    const float* gat_W    = (const float*)d_in[9];
    const float* gat_as   = (const float*)d_in[10];
    const float* gat_ad   = (const float*)d_in[11];
    const float* gat_We   = (const float*)d_in[12];
    const float* gat_ae   = (const float*)d_in[13];
    const float* gat_b    = (const float*)d_in[14];
    const float* bn1_w = (const float*)d_in[15]; const float* bn1_b = (const float*)d_in[16];
    const float* bn1_m = (const float*)d_in[17]; const float* bn1_v = (const float*)d_in[18];
    const float* bn2_w = (const float*)d_in[19]; const float* bn2_b = (const float*)d_in[20];
    const float* bn2_m = (const float*)d_in[21]; const float* bn2_v = (const float*)d_in[22];
    const float* bn3_w = (const float*)d_in[23]; const float* bn3_b = (const float*)d_in[24];
    const float* bn3_m = (const float*)d_in[25]; const float* bn3_v = (const float*)d_in[26];
    const float* m_in_W   = (const float*)d_in[27];
    const float* m_conv_w = (const float*)d_in[28];
    const float* m_conv_b = (const float*)d_in[29];
    const float* m_xp_W   = (const float*)d_in[30];
    const float* m_dt_W   = (const float*)d_in[31];
    const float* m_dt_b   = (const float*)d_in[32];
    const float* m_Alog   = (const float*)d_in[33];
    const float* m_D      = (const float*)d_in[34];
    const float* m_out_W  = (const float*)d_in[35];
    const float* mlp_W1 = (const float*)d_in[36]; const float* mlp_b1 = (const float*)d_in[37];
    const float* mlp_W2 = (const float*)d_in[38]; const float* mlp_b2 = (const float*)d_in[39];
    const float* f_W1 = (const float*)d_in[40]; const float* f_b1 = (const float*)d_in[41];
    const float* f_W2 = (const float*)d_in[42]; const float* f_b2 = (const float*)d_in[43];
    const float* f_W3 = (const float*)d_in[44]; const float* f_b3 = (const float*)d_in[45];

    const int* src = eidx;
    const int* dst = eidx + NEDGES;

    float* wsf = (float*)d_ws;
    const size_t NN80 = (size_t)NNODES*80;
    size_t O_CONSTS = 0;
    size_t O_SUMAE  = 1024;
    size_t O_CNT    = O_SUMAE + NNODES;          // int
    size_t O_POOLED = O_CNT + NNODES;
    size_t O_AE     = O_POOLED + 4000;
    size_t O_AS     = O_AE + NEDGES;
    size_t O_AD     = O_AS + NNODES;
    size_t O_ASELF  = O_AD + NNODES;
    size_t O_ROWPTR = O_ASELF + NNODES;          // int
    size_t O_CURSOR = O_ROWPTR + NNODES;         // int
    size_t O_BSUM   = O_CURSOR + NNODES;         // int, 256
    size_t O_EBUF   = O_BSUM + 256;              // int2 x NEDGES (8B aligned)
    size_t O_H      = O_EBUF + 2*(size_t)NEDGES; // h, later s1
    size_t O_HG     = O_H + NN80;                // hg, later yraw
    size_t O_HGBN   = O_HG + NN80;
    size_t O_XC     = O_HGBN + NN80;
    size_t O_SZ     = O_XC + NN80;
    size_t O_U      = O_SZ + NN80;
    size_t O_DT     = O_U + NN80;
    size_t O_BM     = O_DT + NN80;
    size_t O_CM     = O_BM + (size_t)NNODES*16;

    // zero: sum_ae, cnt, pooled (contiguous)
    hipMemsetAsync(wsf + O_SUMAE, 0, (2*(size_t)NNODES + 4000)*sizeof(float), stream);

    k_precompute<<<1, 256, 0, stream>>>(gat_W, gat_as, gat_ad, gat_We, gat_ae,
        W_edge, b_edge, edge_emb,
        bn1_w, bn1_b, bn1_m, bn1_v, bn2_w, bn2_b, bn2_m, bn2_v, bn3_w, bn3_b, bn3_m, bn3_v,
        wsf + O_CONSTS);

    k_feat<<<(NNODES + 63)/64, 256, 0, stream>>>(x, W_uni, b_uni, wsf + O_H);

    k_edge_scalar<<<(NEDGES + 255)/256, 256, 0, stream>>>(ea_cont, ea_cat, dst,
        wsf + O_CONSTS, wsf + O_AE, wsf + O_SUMAE, (int*)(wsf + O_CNT));

    k_gemm_rows<80, 80, 8, 0><<<(NNODES + 31)/32, 320, 0, stream>>>(
        wsf + O_H, gat_W, wsf + O_HG, nullptr, nullptr, wsf + O_CONSTS, NNODES);

    k_node_as<<<(NNODES + 255)/256, 256, 0, stream>>>(wsf + O_H, wsf + O_CONSTS,
        wsf + O_SUMAE, (const int*)(wsf + O_CNT), wsf + O_AS, wsf + O_AD, wsf + O_ASELF);

    k_psum1<<<NB_SCAN, 256, 0, stream>>>((const int*)(wsf + O_CNT), (int*)(wsf + O_BSUM));
    k_psum2<<<1, 256, 0, stream>>>((int*)(wsf + O_BSUM));
    k_psum3<<<NB_SCAN, 256, 0, stream>>>((const int*)(wsf + O_CNT),
        (const int*)(wsf + O_BSUM), (int*)(wsf + O_ROWPTR), (int*)(wsf + O_CURSOR));

    k_bucket<<<(NEDGES + 255)/256, 256, 0, stream>>>(src, dst, wsf + O_AS,
        wsf + O_AD, wsf + O_AE, (int*)(wsf + O_CURSOR), (int2*)(wsf + O_EBUF));

    k_gat_agg<<<NNODES/16, 256, 0, stream>>>((const int*)(wsf + O_ROWPTR),
        (const int*)(wsf + O_CNT), (const int2*)(wsf + O_EBUF), wsf + O_ASELF,
        wsf + O_HG, gat_b, wsf + O_CONSTS, wsf + O_HGBN);

    k_gemm_rows<80, 160, 8, 1><<<(NNODES + 15)/16, 320, 0, stream>>>(
        wsf + O_H, m_in_W, wsf + O_XC, wsf + O_SZ, nullptr, wsf + O_CONSTS, NNODES);

    k_conv_proj<<<NGRAPHS*25, 256, 0, stream>>>(wsf + O_XC, m_conv_w, m_conv_b,
        m_xp_W, m_dt_W, m_dt_b, wsf + O_U, wsf + O_BM, wsf + O_CM, wsf + O_DT);

    k_scan<<<NGRAPHS*5, 256, 0, stream>>>(wsf + O_DT, wsf + O_U, wsf + O_BM,
        wsf + O_CM, m_Alog, m_D, wsf + O_SZ, wsf + O_HG /*yraw*/);

    k_gemm_rows<80, 80, 8, 2><<<(NNODES + 31)/32, 320, 0, stream>>>(
        wsf + O_HG /*yraw*/, m_out_W, wsf + O_H /*s1*/, nullptr,
        wsf + O_HGBN, wsf + O_CONSTS, NNODES);

    k_mlp<<<NNODES/4, 640, 0, stream>>>(wsf + O_H /*s1*/, mlp_W1, mlp_b1,
        mlp_W2, mlp_b2, wsf + O_CONSTS, wsf + O_POOLED);

    k_pool_final<<<1, 256, 0, stream>>>(wsf + O_POOLED, f_W1, f_b1, f_W2, f_b2,
        f_W3, f_b3, (float*)d_out);
}

// Round 4
// 1232.826 us; speedup vs baseline: 1.2578x; 1.2578x over previous
//
#include <hip/hip_runtime.h>
#include <hip/hip_bf16.h>
#include <cstdint>

#define NNODES 50000
#define NEDGES 800000
#define NGRAPHS 50
#define NPG 1000
#define NB_SCAN 196   // ceil(50000/256)
#define NCHUNK 10
#define CLEN 100      // NPG / NCHUNK

// consts layout (floats) in ws[0..1023]
#define CO_WEAE 0
#define CO_WEC2 16
#define CO_BES  18
#define CO_EMBS 20
#define CO_WS   48
#define CO_WD   128
#define CO_BN1S 208
#define CO_BN1SH 288
#define CO_BN2S 368
#define CO_BN2SH 448
#define CO_BN3S 528
#define CO_BN3SH 608

__device__ __forceinline__ float lrelu(float x){ return x >= 0.f ? x : 0.2f*x; }
__device__ __forceinline__ float siluf(float x){ return x / (1.f + __expf(-x)); }

__device__ __forceinline__ int wave_incl_scan(int v) {
    int lane = threadIdx.x & 63;
    #pragma unroll
    for (int d = 1; d < 64; d <<= 1) {
        int o = __shfl_up(v, d, 64);
        if (lane >= d) v += o;
    }
    return v;
}

// ---------------- precompute folded constants ----------------
__global__ __launch_bounds__(256) void k_precompute(
        const float* __restrict__ gat_W, const float* __restrict__ gat_as, const float* __restrict__ gat_ad,
        const float* __restrict__ gat_We, const float* __restrict__ gat_ae,
        const float* __restrict__ W_edge, const float* __restrict__ b_edge, const float* __restrict__ edge_emb,
        const float* __restrict__ bn1_w, const float* __restrict__ bn1_b, const float* __restrict__ bn1_m, const float* __restrict__ bn1_v,
        const float* __restrict__ bn2_w, const float* __restrict__ bn2_b, const float* __restrict__ bn2_m, const float* __restrict__ bn2_v,
        const float* __restrict__ bn3_w, const float* __restrict__ bn3_b, const float* __restrict__ bn3_m, const float* __restrict__ bn3_v,
        float* __restrict__ consts)
{
    __shared__ float weae[16];
    int tid = threadIdx.x;
    if (tid < 16) {
        float s = 0.f;
        for (int c = 0; c < 80; ++c) s += gat_We[tid*80 + c] * gat_ae[c];
        weae[tid] = s;
        consts[CO_WEAE + tid] = s;
    }
    __syncthreads();
    if (tid < 2) {
        float s = 0.f;
        for (int k = 0; k < 16; ++k) s += W_edge[tid*16 + k] * weae[k];
        consts[CO_WEC2 + tid] = s;
    } else if (tid == 2) {
        float s = 0.f;
        for (int k = 0; k < 16; ++k) s += b_edge[k] * weae[k];
        consts[CO_BES] = s;
    }
    if (tid >= 32 && tid < 53) {
        int j = tid - 32;
        float s = 0.f;
        for (int k = 0; k < 16; ++k) s += edge_emb[j*16 + k] * weae[k];
        consts[CO_EMBS + j] = s;
    }
    if (tid >= 64 && tid < 144) {
        int r = tid - 64;
        float s1 = 0.f, s2 = 0.f;
        for (int c = 0; c < 80; ++c) {
            float w = gat_W[r*80 + c];
            s1 += w * gat_as[c];
            s2 += w * gat_ad[c];
        }
        consts[CO_WS + r] = s1;
        consts[CO_WD + r] = s2;
    }
    if (tid >= 160 && tid < 240) {
        int c = tid - 160;
        float sc1 = bn1_w[c] / sqrtf(bn1_v[c] + 1e-5f);
        consts[CO_BN1S + c] = sc1; consts[CO_BN1SH + c] = bn1_b[c] - bn1_m[c]*sc1;
        float sc2 = bn2_w[c] / sqrtf(bn2_v[c] + 1e-5f);
        consts[CO_BN2S + c] = sc2; consts[CO_BN2SH + c] = bn2_b[c] - bn2_m[c]*sc2;
        float sc3 = bn3_w[c] / sqrtf(bn3_v[c] + 1e-5f);
        consts[CO_BN3S + c] = sc3; consts[CO_BN3SH + c] = bn3_b[c] - bn3_m[c]*sc3;
    }
}

// ---------------- node features: xf = x[:,2:1026]@W_uni + b_uni ; pe ----------------
__global__ __launch_bounds__(256) void k_feat(const float* __restrict__ x,
        const float* __restrict__ W, const float* __restrict__ b,
        float* __restrict__ h)
{
    __shared__ float As[32][68];   // [k][row], padded
    __shared__ float Bs[32][64];   // [k][col]
    int tid = threadIdx.x;
    int node0 = blockIdx.x * 64;
    int tx = tid & 15, ty = tid >> 4;
    float acc[4][4] = {};
    int lr = tid >> 2;            // A-load row 0..63
    int lk = (tid & 3) * 8;       // A-load k base
    int bk = tid >> 3;            // B-load k 0..31
    int bc = (tid & 7) * 8;       // B-load col base
    for (int kk = 0; kk < 1024; kk += 32) {
        int n = node0 + lr;
        if (n < NNODES) {
            const float* xp = x + (size_t)n*1026 + 2 + kk + lk;
            #pragma unroll
            for (int j = 0; j < 8; ++j) As[lk+j][lr] = xp[j];
        } else {
            #pragma unroll
            for (int j = 0; j < 8; ++j) As[lk+j][lr] = 0.f;
        }
        const float* wp = W + (size_t)(kk+bk)*64 + bc;
        #pragma unroll
        for (int j = 0; j < 8; ++j) Bs[bk][bc+j] = wp[j];
        __syncthreads();
        #pragma unroll 8
        for (int i = 0; i < 32; ++i) {
            const float4 a  = *(const float4*)&As[i][ty*4];
            const float4 bb = *(const float4*)&Bs[i][tx*4];
            float av[4] = {a.x, a.y, a.z, a.w};
            float bv[4] = {bb.x, bb.y, bb.z, bb.w};
            #pragma unroll
            for (int r = 0; r < 4; ++r)
                #pragma unroll
                for (int j = 0; j < 4; ++j)
                    acc[r][j] = fmaf(av[r], bv[j], acc[r][j]);
        }
        __syncthreads();
    }
    #pragma unroll
    for (int r = 0; r < 4; ++r) {
        int n = node0 + ty*4 + r;
        if (n < NNODES) {
            #pragma unroll
            for (int j = 0; j < 4; ++j) {
                int c = tx*4 + j;
                h[(size_t)n*80 + c] = acc[r][j] + b[c];
            }
        }
    }
    // positional encoding: cols 64..79
    for (int idx = tid; idx < 64*16; idx += 256) {
        int row = idx >> 4, col = idx & 15;
        int n = node0 + row;
        if (n < NNODES) {
            float pos = x[(size_t)n*1026 + (col < 8 ? 0 : 1)];
            int jj = (col & 7) >> 1;
            const float dens[4] = {1.f, 10.f, 100.f, 1000.f};
            float ang = pos / dens[jj];
            float v = (col & 1) ? cosf(ang) : sinf(ang);
            h[(size_t)n*80 + 64 + col] = v;
        }
    }
}

// ---------------- generic row-GEMM: out[n,c] = sum_k in[n,k] W[k,c] (+epilogue) ----------------
template<int K, int C, int RPT, int EPI>
__global__ __launch_bounds__(320) void k_gemm_rows(const float* __restrict__ in,
        const float* __restrict__ W, float* __restrict__ out, float* __restrict__ out2,
        const float* __restrict__ extra, const float* __restrict__ consts, int N)
{
    constexpr int GROUPS = 320 / C;
    constexpr int NPB = GROUPS * RPT;
    __shared__ float rows[NPB][K];
    int tid = threadIdx.x;
    int n0 = blockIdx.x * NPB;
    for (int idx = tid; idx < NPB*K; idx += 320) {
        int r = idx / K, k = idx - r*K;
        int n = n0 + r;
        rows[r][k] = (n < N) ? in[(size_t)n*K + k] : 0.f;
    }
    __syncthreads();
    int c = tid % C, grp = tid / C;
    float acc[RPT];
    #pragma unroll
    for (int r = 0; r < RPT; ++r) acc[r] = 0.f;
    #pragma unroll 4
    for (int k = 0; k < K; ++k) {
        float w = W[(size_t)k*C + c];
        #pragma unroll
        for (int r = 0; r < RPT; ++r) acc[r] = fmaf(rows[grp*RPT + r][k], w, acc[r]);
    }
    #pragma unroll
    for (int r = 0; r < RPT; ++r) {
        int n = n0 + grp*RPT + r;
        if (n >= N) continue;
        float v = acc[r];
        if (EPI == 0) {
            out[(size_t)n*C + c] = v;
        } else if (EPI == 1) {          // xz: cols<80 -> xc, cols>=80 -> silu(z)
            if (c < 80) out[(size_t)n*80 + c] = v;
            else        out2[(size_t)n*80 + (c-80)] = siluf(v);
        } else if (EPI == 2) {          // bn2 + add hgbn -> s1
            float bv = consts[CO_BN2S + c]*v + consts[CO_BN2SH + c] + extra[(size_t)n*80 + c];
            out[(size_t)n*80 + c] = bv;
        }
    }
}

// ---------------- per-edge scalar attention term + per-dst sums ----------------
__global__ __launch_bounds__(256) void k_edge_scalar(const float* __restrict__ ea_cont,
        const int* __restrict__ ea_cat, const int* __restrict__ dst,
        const float* __restrict__ consts, float* __restrict__ a_e,
        float* __restrict__ sum_ae, int* __restrict__ cnt)
{
    int e = blockIdx.x * 256 + threadIdx.x;
    if (e >= NEDGES) return;
    float2 ec = ((const float2*)ea_cont)[e];
    float v = ec.x*consts[CO_WEC2] + ec.y*consts[CO_WEC2+1] + consts[CO_BES]
            + consts[CO_EMBS + ea_cat[e]];
    a_e[e] = v;
    int d = dst[e];
    atomicAdd(sum_ae + d, v);
    atomicAdd(cnt + d, 1);
}

// ---------------- per-node: a_s, a_d, self-loop alpha ----------------
__global__ __launch_bounds__(256) void k_node_as(const float* __restrict__ h,
        const float* __restrict__ consts, const float* __restrict__ sum_ae,
        const int* __restrict__ cnt, float* __restrict__ a_s, float* __restrict__ a_d,
        float* __restrict__ alpha_self)
{
    __shared__ float wsv[80], wdv[80];
    int tid = threadIdx.x;
    if (tid < 80) { wsv[tid] = consts[CO_WS + tid]; wdv[tid] = consts[CO_WD + tid]; }
    __syncthreads();
    int n = blockIdx.x * 256 + tid;
    if (n >= NNODES) return;
    const float4* hr = (const float4*)(h + (size_t)n*80);
    float as = 0.f, ad = 0.f;
    #pragma unroll 5
    for (int i = 0; i < 20; ++i) {
        float4 f = hr[i];
        as += f.x*wsv[i*4] + f.y*wsv[i*4+1] + f.z*wsv[i*4+2] + f.w*wsv[i*4+3];
        ad += f.x*wdv[i*4] + f.y*wdv[i*4+1] + f.z*wdv[i*4+2] + f.w*wdv[i*4+3];
    }
    float aes = sum_ae[n] / fmaxf((float)cnt[n], 1.f);
    a_s[n] = as; a_d[n] = ad;
    alpha_self[n] = lrelu(as + ad + aes);
}

// ---------------- exclusive scan of cnt -> rowptr (3 kernels) ----------------
__global__ __launch_bounds__(256) void k_psum1(const int* __restrict__ cnt, int* __restrict__ bsum)
{
    __shared__ int ws4[4];
    int tid = threadIdx.x;
    int n = blockIdx.x*256 + tid;
    int v = (n < NNODES) ? cnt[n] : 0;
    int s = wave_incl_scan(v);
    if ((tid & 63) == 63) ws4[tid >> 6] = s;
    __syncthreads();
    if (tid == 0) {
        int t = 0;
        for (int w = 0; w < 4; ++w) t += ws4[w];
        bsum[blockIdx.x] = t;
    }
}

__global__ __launch_bounds__(256) void k_psum2(int* __restrict__ bsum)
{
    __shared__ int wsum[4], woff[4];
    int tid = threadIdx.x;
    int v = (tid < NB_SCAN) ? bsum[tid] : 0;
    int s = wave_incl_scan(v);
    if ((tid & 63) == 63) wsum[tid >> 6] = s;
    __syncthreads();
    if (tid == 0) { int r = 0; for (int w = 0; w < 4; ++w) { woff[w] = r; r += wsum[w]; } }
    __syncthreads();
    int excl = s - v + woff[tid >> 6];
    if (tid < NB_SCAN) bsum[tid] = excl;
}

__global__ __launch_bounds__(256) void k_psum3(const int* __restrict__ cnt,
        const int* __restrict__ bsum, int* __restrict__ rowptr, int* __restrict__ cursor)
{
    __shared__ int wsum[4], woff[4];
    int tid = threadIdx.x;
    int n = blockIdx.x*256 + tid;
    int v = (n < NNODES) ? cnt[n] : 0;
    int s = wave_incl_scan(v);
    if ((tid & 63) == 63) wsum[tid >> 6] = s;
    __syncthreads();
    if (tid == 0) { int r = 0; for (int w = 0; w < 4; ++w) { woff[w] = r; r += wsum[w]; } }
    __syncthreads();
    int excl = s - v + woff[tid >> 6] + bsum[blockIdx.x];
    if (n < NNODES) { rowptr[n] = excl; cursor[n] = excl; }
}

// ---------------- bucket fill: (src, alpha) grouped by dst ----------------
__global__ __launch_bounds__(256) void k_bucket(const int* __restrict__ src,
        const int* __restrict__ dst, const float* __restrict__ a_s,
        const float* __restrict__ a_d, const float* __restrict__ a_e,
        int* __restrict__ cursor, int2* __restrict__ ebuf)
{
    int e = blockIdx.x*256 + threadIdx.x;
    if (e >= NEDGES) return;
    int sN = src[e], d = dst[e];
    float al = lrelu(a_s[sN] + a_d[d] + a_e[e]);
    int pos = atomicAdd(cursor + d, 1);
    ebuf[pos] = make_int2(sN, __float_as_int(al));
}

// ---------------- GAT aggregate (CSR gather): 16 lanes/node ----------------
__global__ __launch_bounds__(256) void k_gat_agg(const int* __restrict__ rowptr,
        const int* __restrict__ cnt, const int2* __restrict__ ebuf,
        const float* __restrict__ alpha_self, const float* __restrict__ hg,
        const float* __restrict__ gat_b, const float* __restrict__ consts,
        float* __restrict__ hgbn)
{
    int tid = threadIdx.x;
    int grp = tid >> 4, l = tid & 15;
    int n = blockIdx.x*16 + grp;
    if (n >= NNODES) return;
    int r0 = rowptr[n], c = cnt[n];
    float aself = alpha_self[n];
    // pass 1: max over edge alphas (lane-strided) + self
    float m = aself;
    for (int i = l; i < c; i += 16)
        m = fmaxf(m, __int_as_float(ebuf[r0 + i].y));
    m = fmaxf(m, __shfl_xor(m, 1, 16));
    m = fmaxf(m, __shfl_xor(m, 2, 16));
    m = fmaxf(m, __shfl_xor(m, 4, 16));
    m = fmaxf(m, __shfl_xor(m, 8, 16));
    // pass 2: softmax-weighted gather; lane l owns channels l+16j
    float ex0 = __expf(aself - m);
    float denom = ex0;
    float acc[5];
    const float* hn = hg + (size_t)n*80;
    #pragma unroll
    for (int j = 0; j < 5; ++j) acc[j] = ex0 * hn[l + 16*j];
    for (int i = 0; i < c; ++i) {
        int2 p = ebuf[r0 + i];
        float ex = __expf(__int_as_float(p.y) - m);
        denom += ex;
        const float* hs = hg + (size_t)p.x*80;
        #pragma unroll
        for (int j = 0; j < 5; ++j) acc[j] = fmaf(ex, hs[l + 16*j], acc[j]);
    }
    float inv = 1.f/denom;
    #pragma unroll
    for (int j = 0; j < 5; ++j) {
        int ch = l + 16*j;
        float v = acc[j]*inv + gat_b[ch];
        hgbn[(size_t)n*80 + ch] = consts[CO_BN1S + ch]*v + consts[CO_BN1SH + ch];
    }
}

// ---------------- mamba: depthwise conv + silu, x_proj, dt ----------------
__global__ __launch_bounds__(256) void k_conv_proj(const float* __restrict__ xc,
        const float* __restrict__ conv_w, const float* __restrict__ conv_b,
        const float* __restrict__ xp_W, const float* __restrict__ dt_W,
        const float* __restrict__ dt_b, float* __restrict__ u_g,
        float* __restrict__ Bm, float* __restrict__ Cm, float* __restrict__ dt_g)
{
    __shared__ float us[40][80];
    __shared__ float dtr[40][5];
    int g = blockIdx.x / 25, chunk = blockIdx.x % 25;
    int t0 = chunk * 40;
    int tid = threadIdx.x;
    size_t gbase = (size_t)g * NPG;
    for (int idx = tid; idx < 40*80; idx += 256) {
        int t = idx / 80, d = idx - t*80;
        int tt = t0 + t;
        float acc = conv_b[d];
        #pragma unroll
        for (int k = 0; k < 4; ++k) {
            int ti = tt - 3 + k;
            float xv = (ti >= 0) ? xc[(gbase + ti)*80 + d] : 0.f;
            acc = fmaf(xv, conv_w[d*4 + k], acc);
        }
        float uv = siluf(acc);
        us[t][d] = uv;
        u_g[(gbase + tt)*80 + d] = uv;
    }
    __syncthreads();
    for (int idx = tid; idx < 40*37; idx += 256) {
        int t = idx / 37, j = idx - t*37;
        float acc = 0.f;
        #pragma unroll 4
        for (int k = 0; k < 80; ++k) acc = fmaf(us[t][k], xp_W[k*37 + j], acc);
        int tt = t0 + t;
        if (j < 5) dtr[t][j] = acc;
        else if (j < 21) Bm[(gbase + tt)*16 + (j-5)] = acc;
        else Cm[(gbase + tt)*16 + (j-21)] = acc;
    }
    __syncthreads();
    for (int idx = tid; idx < 40*80; idx += 256) {
        int t = idx / 80, d = idx - t*80;
        float acc = dt_b[d];
        #pragma unroll
        for (int r = 0; r < 5; ++r) acc = fmaf(dtr[t][r], dt_W[r*80 + d], acc);
        float sp = (acc > 20.f) ? acc : log1pf(__expf(acc));
        dt_g[(gbase + t0 + t)*80 + d] = sp;
    }
}

// ---------------- SSM chunked scan, phase A: per-chunk (P = prod dA, Q = h_end|h0=0) ----------------
__global__ __launch_bounds__(256) void k_scan_a(const float* __restrict__ dt,
        const float* __restrict__ u, const float* __restrict__ Bm,
        const float* __restrict__ A_log, float* __restrict__ Pb, float* __restrict__ Qb)
{
    int b = blockIdx.x;               // b = (g*5 + dblk)*NCHUNK + c
    int c = b % NCHUNK; int gd = b / NCHUNK;
    int g = gd / 5, dblk = gd % 5;
    int dl = threadIdx.x >> 4, s = threadIdx.x & 15;
    int d = dblk*16 + dl;
    float a = -__expf(A_log[d*16 + s]);
    size_t base80 = (size_t)g*NPG*80 + (size_t)c*CLEN*80 + d;
    size_t base16 = (size_t)g*NPG*16 + (size_t)c*CLEN*16 + s;
    float P = 1.f, Q = 0.f;
    for (int t = 0; t < CLEN; ++t) {
        float dtv = dt[base80 + (size_t)t*80];
        float uv  = u [base80 + (size_t)t*80];
        float Bv  = Bm[base16 + (size_t)t*16];
        float dA = __expf(dtv * a);
        Q = fmaf(dA, Q, dtv*uv*Bv);
        P *= dA;
    }
    size_t o = ((size_t)(g*NCHUNK + c)*80 + d)*16 + s;
    Pb[o] = P; Qb[o] = Q;
}

// ---------------- SSM chunked scan, phase C: combine h_start, emit y ----------------
__global__ __launch_bounds__(256) void k_scan_c(const float* __restrict__ dt,
        const float* __restrict__ u, const float* __restrict__ Bm,
        const float* __restrict__ Cm, const float* __restrict__ A_log,
        const float* __restrict__ Dp, const float* __restrict__ sz,
        const float* __restrict__ Pb, const float* __restrict__ Qb,
        float* __restrict__ yraw)
{
    int b = blockIdx.x;
    int c = b % NCHUNK; int gd = b / NCHUNK;
    int g = gd / 5, dblk = gd % 5;
    int dl = threadIdx.x >> 4, s = threadIdx.x & 15;
    int d = dblk*16 + dl;
    float a = -__expf(A_log[d*16 + s]);
    float Dd = Dp[d];
    // combine starting state from earlier chunks (L2-resident, <=9 iters)
    float hst = 0.f;
    for (int cc = 0; cc < c; ++cc) {
        size_t o = ((size_t)(g*NCHUNK + cc)*80 + d)*16 + s;
        hst = fmaf(Pb[o], hst, Qb[o]);
    }
    size_t base80 = (size_t)g*NPG*80 + (size_t)c*CLEN*80 + d;
    size_t base16 = (size_t)g*NPG*16 + (size_t)c*CLEN*16 + s;
    for (int t = 0; t < CLEN; ++t) {
        float dtv = dt[base80 + (size_t)t*80];
        float uv  = u [base80 + (size_t)t*80];
        float Bv  = Bm[base16 + (size_t)t*16];
        float Cv  = Cm[base16 + (size_t)t*16];
        float dA = __expf(dtv * a);
        hst = fmaf(dA, hst, dtv*uv*Bv);
        float cv = hst * Cv;
        cv += __shfl_xor(cv, 1, 16);
        cv += __shfl_xor(cv, 2, 16);
        cv += __shfl_xor(cv, 4, 16);
        cv += __shfl_xor(cv, 8, 16);
        if (s == 0) {
            size_t i = base80 + (size_t)t*80;
            yraw[i] = (cv + uv*Dd) * sz[i];
        }
    }
}

// ---------------- residual MLP + bn3 + relu + pooled accumulation ----------------
__global__ __launch_bounds__(640) void k_mlp(const float* __restrict__ s1,
        const float* __restrict__ W1, const float* __restrict__ b1,
        const float* __restrict__ W2, const float* __restrict__ b2,
        const float* __restrict__ consts, float* __restrict__ pooled)
{
    __shared__ float s1s[4][80];
    __shared__ float t1s[4][160];
    int tid = threadIdx.x;
    int n0 = blockIdx.x * 4;
    if (tid < 320) {
        int r = tid / 80, c = tid - r*80;
        s1s[r][c] = s1[(size_t)(n0 + r)*80 + c];
    }
    __syncthreads();
    {
        int r = tid / 160, j = tid - (tid/160)*160;
        float acc = b1[j];
        #pragma unroll 4
        for (int k = 0; k < 80; ++k) acc = fmaf(s1s[r][k], W1[k*160 + j], acc);
        t1s[r][j] = fmaxf(acc, 0.f);
    }
    __syncthreads();
    if (tid < 320) {
        int r = tid / 80, c = tid - (tid/80)*80;
        float acc = b2[c];
        #pragma unroll 4
        for (int k = 0; k < 160; ++k) acc = fmaf(t1s[r][k], W2[k*80 + c], acc);
        float v = s1s[r][c] + acc;
        v = consts[CO_BN3S + c]*v + consts[CO_BN3SH + c];
        v = fmaxf(v, 0.f);
        s1s[r][c] = v;
    }
    __syncthreads();
    if (tid < 80) {
        float sum = s1s[0][tid] + s1s[1][tid] + s1s[2][tid] + s1s[3][tid];
        atomicAdd(pooled + (n0 / NPG)*80 + tid, sum);
    }
}

// ---------------- pooled mean + final 3-layer MLP ----------------
__global__ __launch_bounds__(256) void k_pool_final(const float* __restrict__ pooled,
        const float* __restrict__ f_W1, const float* __restrict__ f_b1,
        const float* __restrict__ f_W2, const float* __restrict__ f_b2,
        const float* __restrict__ f_W3, const float* __restrict__ f_b3,
        float* __restrict__ d_out)
{
    __shared__ float pl[50*80];
    __shared__ float h1[50*40];
    __shared__ float h2[50*20];
    int tid = threadIdx.x;
    for (int idx = tid; idx < 50*80; idx += 256) {
        float v = pooled[idx] * (1.f/NPG);
        pl[idx] = v;
        d_out[50 + idx] = v;
    }
    __syncthreads();
    for (int idx = tid; idx < 50*40; idx += 256) {
        int g = idx / 40, j = idx - g*40;
        float acc = f_b1[j];
        for (int k = 0; k < 80; ++k) acc = fmaf(pl[g*80+k], f_W1[k*40+j], acc);
        h1[idx] = fmaxf(acc, 0.f);
    }
    __syncthreads();
    for (int idx = tid; idx < 50*20; idx += 256) {
        int g = idx / 20, j = idx - g*20;
        float acc = f_b2[j];
        for (int k = 0; k < 40; ++k) acc = fmaf(h1[g*40+k], f_W2[k*20+j], acc);
        h2[idx] = fmaxf(acc, 0.f);
    }
    __syncthreads();
    if (tid < 50) {
        float acc = f_b3[0];
        for (int k = 0; k < 20; ++k) acc = fmaf(h2[tid*20+k], f_W3[k], acc);
        d_out[tid] = acc;
    }
}

extern "C" void kernel_launch(void* const* d_in, const int* in_sizes, int n_in,
                              void* d_out, int out_size, void* d_ws, size_t ws_size,
                              hipStream_t stream)
{
    (void)in_sizes; (void)n_in; (void)out_size; (void)ws_size;
    const float* x        = (const float*)d_in[0];
    const int*   eidx     = (const int*)d_in[1];
    const int*   ea_cat   = (const int*)d_in[2];
    const float* ea_cont  = (const float*)d_in[3];
    const float* W_uni    = (const float*)d_in[4];
    const float* b_uni    = (const float*)d_in[5];
    const float* edge_emb = (const float*)d_in[6];
    const float* W_edge   = (const float*)d_in[7];
    const float* b_edge   = (const float*)d_in[8];
    const float* gat_W    = (const float*)d_in[9];
    const float* gat_as   = (const float*)d_in[10];
    const float* gat_ad   = (const float*)d_in[11];
    const float* gat_We   = (const float*)d_in[12];
    const float* gat_ae   = (const float*)d_in[13];
    const float* gat_b    = (const float*)d_in[14];
    const float* bn1_w = (const float*)d_in[15]; const float* bn1_b = (const float*)d_in[16];
    const float* bn1_m = (const float*)d_in[17]; const float* bn1_v = (const float*)d_in[18];
    const float* bn2_w = (const float*)d_in[19]; const float* bn2_b = (const float*)d_in[20];
    const float* bn2_m = (const float*)d_in[21]; const float* bn2_v = (const float*)d_in[22];
    const float* bn3_w = (const float*)d_in[23]; const float* bn3_b = (const float*)d_in[24];
    const float* bn3_m = (const float*)d_in[25]; const float* bn3_v = (const float*)d_in[26];
    const float* m_in_W   = (const float*)d_in[27];
    const float* m_conv_w = (const float*)d_in[28];
    const float* m_conv_b = (const float*)d_in[29];
    const float* m_xp_W   = (const float*)d_in[30];
    const float* m_dt_W   = (const float*)d_in[31];
    const float* m_dt_b   = (const float*)d_in[32];
    const float* m_Alog   = (const float*)d_in[33];
    const float* m_D      = (const float*)d_in[34];
    const float* m_out_W  = (const float*)d_in[35];
    const float* mlp_W1 = (const float*)d_in[36]; const float* mlp_b1 = (const float*)d_in[37];
    const float* mlp_W2 = (const float*)d_in[38]; const float* mlp_b2 = (const float*)d_in[39];
    const float* f_W1 = (const float*)d_in[40]; const float* f_b1 = (const float*)d_in[41];
    const float* f_W2 = (const float*)d_in[42]; const float* f_b2 = (const float*)d_in[43];
    const float* f_W3 = (const float*)d_in[44]; const float* f_b3 = (const float*)d_in[45];

    const int* src = eidx;
    const int* dst = eidx + NEDGES;

    float* wsf = (float*)d_ws;
    const size_t NN80 = (size_t)NNODES*80;
    size_t O_CONSTS = 0;
    size_t O_SUMAE  = 1024;
    size_t O_CNT    = O_SUMAE + NNODES;          // int
    size_t O_POOLED = O_CNT + NNODES;
    size_t O_AE     = O_POOLED + 4000;
    size_t O_AS     = O_AE + NEDGES;
    size_t O_AD     = O_AS + NNODES;
    size_t O_ASELF  = O_AD + NNODES;
    size_t O_ROWPTR = O_ASELF + NNODES;          // int
    size_t O_CURSOR = O_ROWPTR + NNODES;         // int
    size_t O_BSUM   = O_CURSOR + NNODES;         // int, 256
    size_t O_EBUF   = O_BSUM + 256;              // int2 x NEDGES (8B aligned); dead after k_gat_agg
    size_t O_PB     = O_EBUF;                    // reuse: 640000 floats
    size_t O_QB     = O_EBUF + 640000;           // reuse: 640000 floats
    size_t O_H      = O_EBUF + 2*(size_t)NEDGES; // h, later s1
    size_t O_HG     = O_H + NN80;                // hg, later yraw
    size_t O_HGBN   = O_HG + NN80;
    size_t O_XC     = O_HGBN + NN80;
    size_t O_SZ     = O_XC + NN80;
    size_t O_U      = O_SZ + NN80;
    size_t O_DT     = O_U + NN80;
    size_t O_BM     = O_DT + NN80;
    size_t O_CM     = O_BM + (size_t)NNODES*16;

    // zero: sum_ae, cnt, pooled (contiguous)
    hipMemsetAsync(wsf + O_SUMAE, 0, (2*(size_t)NNODES + 4000)*sizeof(float), stream);

    k_precompute<<<1, 256, 0, stream>>>(gat_W, gat_as, gat_ad, gat_We, gat_ae,
        W_edge, b_edge, edge_emb,
        bn1_w, bn1_b, bn1_m, bn1_v, bn2_w, bn2_b, bn2_m, bn2_v, bn3_w, bn3_b, bn3_m, bn3_v,
        wsf + O_CONSTS);

    k_feat<<<(NNODES + 63)/64, 256, 0, stream>>>(x, W_uni, b_uni, wsf + O_H);

    k_edge_scalar<<<(NEDGES + 255)/256, 256, 0, stream>>>(ea_cont, ea_cat, dst,
        wsf + O_CONSTS, wsf + O_AE, wsf + O_SUMAE, (int*)(wsf + O_CNT));

    k_gemm_rows<80, 80, 8, 0><<<(NNODES + 31)/32, 320, 0, stream>>>(
        wsf + O_H, gat_W, wsf + O_HG, nullptr, nullptr, wsf + O_CONSTS, NNODES);

    k_node_as<<<(NNODES + 255)/256, 256, 0, stream>>>(wsf + O_H, wsf + O_CONSTS,
        wsf + O_SUMAE, (const int*)(wsf + O_CNT), wsf + O_AS, wsf + O_AD, wsf + O_ASELF);

    k_psum1<<<NB_SCAN, 256, 0, stream>>>((const int*)(wsf + O_CNT), (int*)(wsf + O_BSUM));
    k_psum2<<<1, 256, 0, stream>>>((int*)(wsf + O_BSUM));
    k_psum3<<<NB_SCAN, 256, 0, stream>>>((const int*)(wsf + O_CNT),
        (const int*)(wsf + O_BSUM), (int*)(wsf + O_ROWPTR), (int*)(wsf + O_CURSOR));

    k_bucket<<<(NEDGES + 255)/256, 256, 0, stream>>>(src, dst, wsf + O_AS,
        wsf + O_AD, wsf + O_AE, (int*)(wsf + O_CURSOR), (int2*)(wsf + O_EBUF));

    k_gat_agg<<<NNODES/16, 256, 0, stream>>>((const int*)(wsf + O_ROWPTR),
        (const int*)(wsf + O_CNT), (const int2*)(wsf + O_EBUF), wsf + O_ASELF,
        wsf + O_HG, gat_b, wsf + O_CONSTS, wsf + O_HGBN);

    k_gemm_rows<80, 160, 8, 1><<<(NNODES + 15)/16, 320, 0, stream>>>(
        wsf + O_H, m_in_W, wsf + O_XC, wsf + O_SZ, nullptr, wsf + O_CONSTS, NNODES);

    k_conv_proj<<<NGRAPHS*25, 256, 0, stream>>>(wsf + O_XC, m_conv_w, m_conv_b,
        m_xp_W, m_dt_W, m_dt_b, wsf + O_U, wsf + O_BM, wsf + O_CM, wsf + O_DT);

    // chunked SSM scan (ebuf region reused for P/Q — dead after k_gat_agg)
    k_scan_a<<<NGRAPHS*5*NCHUNK, 256, 0, stream>>>(wsf + O_DT, wsf + O_U,
        wsf + O_BM, m_Alog, wsf + O_PB, wsf + O_QB);

    k_scan_c<<<NGRAPHS*5*NCHUNK, 256, 0, stream>>>(wsf + O_DT, wsf + O_U,
        wsf + O_BM, wsf + O_CM, m_Alog, m_D, wsf + O_SZ,
        wsf + O_PB, wsf + O_QB, wsf + O_HG /*yraw*/);

    k_gemm_rows<80, 80, 8, 2><<<(NNODES + 31)/32, 320, 0, stream>>>(
        wsf + O_HG /*yraw*/, m_out_W, wsf + O_H /*s1*/, nullptr,
        wsf + O_HGBN, wsf + O_CONSTS, NNODES);

    k_mlp<<<NNODES/4, 640, 0, stream>>>(wsf + O_H /*s1*/, mlp_W1, mlp_b1,
        mlp_W2, mlp_b2, wsf + O_CONSTS, wsf + O_POOLED);

    k_pool_final<<<1, 256, 0, stream>>>(wsf + O_POOLED, f_W1, f_b1, f_W2, f_b2,
        f_W3, f_b3, (float*)d_out);
}

// Round 6
// 1112.755 us; speedup vs baseline: 1.3936x; 1.1079x over previous
//
#include <hip/hip_runtime.h>
#include <hip/hip_bf16.h>
#include <cstdint>

#define NNODES 50000
#define NEDGES 800000
#define NGRAPHS 50
#define NPG 1000
#define NB_SCAN 196   // ceil(50000/256)
#define NCHUNK 10
#define CLEN 100      // NPG / NCHUNK

// consts layout (floats) in ws[0..1023]
#define CO_WEAE 0
#define CO_WEC2 16
#define CO_BES  18
#define CO_EMBS 20
#define CO_WS   48
#define CO_WD   128
#define CO_BN1S 208
#define CO_BN1SH 288
#define CO_BN2S 368
#define CO_BN2SH 448
#define CO_BN3S 528
#define CO_BN3SH 608

__device__ __forceinline__ float lrelu(float x){ return x >= 0.f ? x : 0.2f*x; }
__device__ __forceinline__ float siluf(float x){ return x / (1.f + __expf(-x)); }

__device__ __forceinline__ int wave_incl_scan(int v) {
    int lane = threadIdx.x & 63;
    #pragma unroll
    for (int d = 1; d < 64; d <<= 1) {
        int o = __shfl_up(v, d, 64);
        if (lane >= d) v += o;
    }
    return v;
}

// ---------------- precompute folded constants ----------------
__global__ __launch_bounds__(256) void k_precompute(
        const float* __restrict__ gat_W, const float* __restrict__ gat_as, const float* __restrict__ gat_ad,
        const float* __restrict__ gat_We, const float* __restrict__ gat_ae,
        const float* __restrict__ W_edge, const float* __restrict__ b_edge, const float* __restrict__ edge_emb,
        const float* __restrict__ bn1_w, const float* __restrict__ bn1_b, const float* __restrict__ bn1_m, const float* __restrict__ bn1_v,
        const float* __restrict__ bn2_w, const float* __restrict__ bn2_b, const float* __restrict__ bn2_m, const float* __restrict__ bn2_v,
        const float* __restrict__ bn3_w, const float* __restrict__ bn3_b, const float* __restrict__ bn3_m, const float* __restrict__ bn3_v,
        float* __restrict__ consts)
{
    __shared__ float weae[16];
    int tid = threadIdx.x;
    if (tid < 16) {
        float s = 0.f;
        for (int c = 0; c < 80; ++c) s += gat_We[tid*80 + c] * gat_ae[c];
        weae[tid] = s;
        consts[CO_WEAE + tid] = s;
    }
    __syncthreads();
    if (tid < 2) {
        float s = 0.f;
        for (int k = 0; k < 16; ++k) s += W_edge[tid*16 + k] * weae[k];
        consts[CO_WEC2 + tid] = s;
    } else if (tid == 2) {
        float s = 0.f;
        for (int k = 0; k < 16; ++k) s += b_edge[k] * weae[k];
        consts[CO_BES] = s;
    }
    if (tid >= 32 && tid < 53) {
        int j = tid - 32;
        float s = 0.f;
        for (int k = 0; k < 16; ++k) s += edge_emb[j*16 + k] * weae[k];
        consts[CO_EMBS + j] = s;
    }
    if (tid >= 64 && tid < 144) {
        int r = tid - 64;
        float s1 = 0.f, s2 = 0.f;
        for (int c = 0; c < 80; ++c) {
            float w = gat_W[r*80 + c];
            s1 += w * gat_as[c];
            s2 += w * gat_ad[c];
        }
        consts[CO_WS + r] = s1;
        consts[CO_WD + r] = s2;
    }
    if (tid >= 160 && tid < 240) {
        int c = tid - 160;
        float sc1 = bn1_w[c] / sqrtf(bn1_v[c] + 1e-5f);
        consts[CO_BN1S + c] = sc1; consts[CO_BN1SH + c] = bn1_b[c] - bn1_m[c]*sc1;
        float sc2 = bn2_w[c] / sqrtf(bn2_v[c] + 1e-5f);
        consts[CO_BN2S + c] = sc2; consts[CO_BN2SH + c] = bn2_b[c] - bn2_m[c]*sc2;
        float sc3 = bn3_w[c] / sqrtf(bn3_v[c] + 1e-5f);
        consts[CO_BN3S + c] = sc3; consts[CO_BN3SH + c] = bn3_b[c] - bn3_m[c]*sc3;
    }
}

// ---------------- node features: xf = x[:,2:1026]@W_uni + b_uni ; pe ----------------
__global__ __launch_bounds__(256) void k_feat(const float* __restrict__ x,
        const float* __restrict__ W, const float* __restrict__ b,
        float* __restrict__ h)
{
    __shared__ float As[32][68];   // [k][row], padded
    __shared__ float Bs[32][64];   // [k][col]
    int tid = threadIdx.x;
    int node0 = blockIdx.x * 64;
    int tx = tid & 15, ty = tid >> 4;
    float acc[4][4] = {};
    int lr = tid >> 2;            // A-load row 0..63
    int lk = (tid & 3) * 8;       // A-load k base
    int bk = tid >> 3;            // B-load k 0..31
    int bc = (tid & 7) * 8;       // B-load col base
    for (int kk = 0; kk < 1024; kk += 32) {
        int n = node0 + lr;
        if (n < NNODES) {
            const float* xp = x + (size_t)n*1026 + 2 + kk + lk;
            #pragma unroll
            for (int j = 0; j < 8; ++j) As[lk+j][lr] = xp[j];
        } else {
            #pragma unroll
            for (int j = 0; j < 8; ++j) As[lk+j][lr] = 0.f;
        }
        const float* wp = W + (size_t)(kk+bk)*64 + bc;
        #pragma unroll
        for (int j = 0; j < 8; ++j) Bs[bk][bc+j] = wp[j];
        __syncthreads();
        #pragma unroll 8
        for (int i = 0; i < 32; ++i) {
            const float4 a  = *(const float4*)&As[i][ty*4];
            const float4 bb = *(const float4*)&Bs[i][tx*4];
            float av[4] = {a.x, a.y, a.z, a.w};
            float bv[4] = {bb.x, bb.y, bb.z, bb.w};
            #pragma unroll
            for (int r = 0; r < 4; ++r)
                #pragma unroll
                for (int j = 0; j < 4; ++j)
                    acc[r][j] = fmaf(av[r], bv[j], acc[r][j]);
        }
        __syncthreads();
    }
    #pragma unroll
    for (int r = 0; r < 4; ++r) {
        int n = node0 + ty*4 + r;
        if (n < NNODES) {
            #pragma unroll
            for (int j = 0; j < 4; ++j) {
                int c = tx*4 + j;
                h[(size_t)n*80 + c] = acc[r][j] + b[c];
            }
        }
    }
    // positional encoding: cols 64..79
    for (int idx = tid; idx < 64*16; idx += 256) {
        int row = idx >> 4, col = idx & 15;
        int n = node0 + row;
        if (n < NNODES) {
            float pos = x[(size_t)n*1026 + (col < 8 ? 0 : 1)];
            int jj = (col & 7) >> 1;
            const float dens[4] = {1.f, 10.f, 100.f, 1000.f};
            float ang = pos / dens[jj];
            float v = (col & 1) ? cosf(ang) : sinf(ang);
            h[(size_t)n*80 + 64 + col] = v;
        }
    }
}

// ---------------- generic row-GEMM: out[n,c] = sum_k in[n,k] W[k,c] (+epilogue) ----------------
// EPI 0: raw. 1: xz split (silu z). 2: bn2 + extra add. 3: relu(v + bias).
// EPI 4: v + bias + extra(residual, stride 80) -> bn3 -> relu.
template<int K, int C, int RPT, int EPI>
__global__ __launch_bounds__(320) void k_gemm_rows(const float* __restrict__ in,
        const float* __restrict__ W, float* __restrict__ out, float* __restrict__ out2,
        const float* __restrict__ extra, const float* __restrict__ bias,
        const float* __restrict__ consts, int N)
{
    constexpr int GROUPS = 320 / C;
    constexpr int NPB = GROUPS * RPT;
    __shared__ float rows[NPB][K];
    int tid = threadIdx.x;
    int n0 = blockIdx.x * NPB;
    for (int idx = tid; idx < NPB*K; idx += 320) {
        int r = idx / K, k = idx - r*K;
        int n = n0 + r;
        rows[r][k] = (n < N) ? in[(size_t)n*K + k] : 0.f;
    }
    __syncthreads();
    int c = tid % C, grp = tid / C;
    float acc[RPT];
    #pragma unroll
    for (int r = 0; r < RPT; ++r) acc[r] = 0.f;
    #pragma unroll 4
    for (int k = 0; k < K; ++k) {
        float w = W[(size_t)k*C + c];
        #pragma unroll
        for (int r = 0; r < RPT; ++r) acc[r] = fmaf(rows[grp*RPT + r][k], w, acc[r]);
    }
    #pragma unroll
    for (int r = 0; r < RPT; ++r) {
        int n = n0 + grp*RPT + r;
        if (n >= N) continue;
        float v = acc[r];
        if (EPI == 0) {
            out[(size_t)n*C + c] = v;
        } else if (EPI == 1) {          // xz: cols<80 -> xc, cols>=80 -> silu(z)
            if (c < 80) out[(size_t)n*80 + c] = v;
            else        out2[(size_t)n*80 + (c-80)] = siluf(v);
        } else if (EPI == 2) {          // bn2 + add hgbn -> s1
            float bv = consts[CO_BN2S + c]*v + consts[CO_BN2SH + c] + extra[(size_t)n*80 + c];
            out[(size_t)n*80 + c] = bv;
        } else if (EPI == 3) {          // relu(v + bias) -> t1
            out[(size_t)n*C + c] = fmaxf(v + bias[c], 0.f);
        } else if (EPI == 4) {          // residual + bias -> bn3 -> relu -> s2
            float bv = v + bias[c] + extra[(size_t)n*80 + c];
            bv = consts[CO_BN3S + c]*bv + consts[CO_BN3SH + c];
            out[(size_t)n*80 + c] = fmaxf(bv, 0.f);
        }
    }
}

// ---------------- per-edge scalar attention term + per-dst sums ----------------
__global__ __launch_bounds__(256) void k_edge_scalar(const float* __restrict__ ea_cont,
        const int* __restrict__ ea_cat, const int* __restrict__ dst,
        const float* __restrict__ consts, float* __restrict__ a_e,
        float* __restrict__ sum_ae, int* __restrict__ cnt)
{
    int e = blockIdx.x * 256 + threadIdx.x;
    if (e >= NEDGES) return;
    float2 ec = ((const float2*)ea_cont)[e];
    float v = ec.x*consts[CO_WEC2] + ec.y*consts[CO_WEC2+1] + consts[CO_BES]
            + consts[CO_EMBS + ea_cat[e]];
    a_e[e] = v;
    int d = dst[e];
    atomicAdd(sum_ae + d, v);
    atomicAdd(cnt + d, 1);
}

// ---------------- per-node: a_s, a_d, self-loop alpha ----------------
__global__ __launch_bounds__(256) void k_node_as(const float* __restrict__ h,
        const float* __restrict__ consts, const float* __restrict__ sum_ae,
        const int* __restrict__ cnt, float* __restrict__ a_s, float* __restrict__ a_d,
        float* __restrict__ alpha_self)
{
    __shared__ float wsv[80], wdv[80];
    int tid = threadIdx.x;
    if (tid < 80) { wsv[tid] = consts[CO_WS + tid]; wdv[tid] = consts[CO_WD + tid]; }
    __syncthreads();
    int n = blockIdx.x * 256 + tid;
    if (n >= NNODES) return;
    const float4* hr = (const float4*)(h + (size_t)n*80);
    float as = 0.f, ad = 0.f;
    #pragma unroll 5
    for (int i = 0; i < 20; ++i) {
        float4 f = hr[i];
        as += f.x*wsv[i*4] + f.y*wsv[i*4+1] + f.z*wsv[i*4+2] + f.w*wsv[i*4+3];
        ad += f.x*wdv[i*4] + f.y*wdv[i*4+1] + f.z*wdv[i*4+2] + f.w*wdv[i*4+3];
    }
    float aes = sum_ae[n] / fmaxf((float)cnt[n], 1.f);
    a_s[n] = as; a_d[n] = ad;
    alpha_self[n] = lrelu(as + ad + aes);
}

// ---------------- exclusive scan of cnt -> rowptr (3 kernels) ----------------
__global__ __launch_bounds__(256) void k_psum1(const int* __restrict__ cnt, int* __restrict__ bsum)
{
    __shared__ int ws4[4];
    int tid = threadIdx.x;
    int n = blockIdx.x*256 + tid;
    int v = (n < NNODES) ? cnt[n] : 0;
    int s = wave_incl_scan(v);
    if ((tid & 63) == 63) ws4[tid >> 6] = s;
    __syncthreads();
    if (tid == 0) {
        int t = 0;
        for (int w = 0; w < 4; ++w) t += ws4[w];
        bsum[blockIdx.x] = t;
    }
}

__global__ __launch_bounds__(256) void k_psum2(int* __restrict__ bsum)
{
    __shared__ int wsum[4], woff[4];
    int tid = threadIdx.x;
    int v = (tid < NB_SCAN) ? bsum[tid] : 0;
    int s = wave_incl_scan(v);
    if ((tid & 63) == 63) wsum[tid >> 6] = s;
    __syncthreads();
    if (tid == 0) { int r = 0; for (int w = 0; w < 4; ++w) { woff[w] = r; r += wsum[w]; } }
    __syncthreads();
    int excl = s - v + woff[tid >> 6];
    if (tid < NB_SCAN) bsum[tid] = excl;
}

__global__ __launch_bounds__(256) void k_psum3(const int* __restrict__ cnt,
        const int* __restrict__ bsum, int* __restrict__ rowptr, int* __restrict__ cursor)
{
    __shared__ int wsum[4], woff[4];
    int tid = threadIdx.x;
    int n = blockIdx.x*256 + tid;
    int v = (n < NNODES) ? cnt[n] : 0;
    int s = wave_incl_scan(v);
    if ((tid & 63) == 63) wsum[tid >> 6] = s;
    __syncthreads();
    if (tid == 0) { int r = 0; for (int w = 0; w < 4; ++w) { woff[w] = r; r += wsum[w]; } }
    __syncthreads();
    int excl = s - v + woff[tid >> 6] + bsum[blockIdx.x];
    if (n < NNODES) { rowptr[n] = excl; cursor[n] = excl; }
}

// ---------------- bucket fill: (src, alpha) grouped by dst ----------------
__global__ __launch_bounds__(256) void k_bucket(const int* __restrict__ src,
        const int* __restrict__ dst, const float* __restrict__ a_s,
        const float* __restrict__ a_d, const float* __restrict__ a_e,
        int* __restrict__ cursor, int2* __restrict__ ebuf)
{
    int e = blockIdx.x*256 + threadIdx.x;
    if (e >= NEDGES) return;
    int sN = src[e], d = dst[e];
    float al = lrelu(a_s[sN] + a_d[d] + a_e[e]);
    int pos = atomicAdd(cursor + d, 1);
    ebuf[pos] = make_int2(sN, __float_as_int(al));
}

// ---------------- GAT aggregate (CSR gather): 16 lanes/node ----------------
__global__ __launch_bounds__(256) void k_gat_agg(const int* __restrict__ rowptr,
        const int* __restrict__ cnt, const int2* __restrict__ ebuf,
        const float* __restrict__ alpha_self, const float* __restrict__ hg,
        const float* __restrict__ gat_b, const float* __restrict__ consts,
        float* __restrict__ hgbn)
{
    int tid = threadIdx.x;
    int grp = tid >> 4, l = tid & 15;
    int n = blockIdx.x*16 + grp;
    if (n >= NNODES) return;
    int r0 = rowptr[n], c = cnt[n];
    float aself = alpha_self[n];
    // pass 1: max over edge alphas (lane-strided) + self
    float m = aself;
    for (int i = l; i < c; i += 16)
        m = fmaxf(m, __int_as_float(ebuf[r0 + i].y));
    m = fmaxf(m, __shfl_xor(m, 1, 16));
    m = fmaxf(m, __shfl_xor(m, 2, 16));
    m = fmaxf(m, __shfl_xor(m, 4, 16));
    m = fmaxf(m, __shfl_xor(m, 8, 16));
    // pass 2: softmax-weighted gather; lane l owns channels l+16j
    float ex0 = __expf(aself - m);
    float denom = ex0;
    float acc[5];
    const float* hn = hg + (size_t)n*80;
    #pragma unroll
    for (int j = 0; j < 5; ++j) acc[j] = ex0 * hn[l + 16*j];
    for (int i = 0; i < c; ++i) {
        int2 p = ebuf[r0 + i];
        float ex = __expf(__int_as_float(p.y) - m);
        denom += ex;
        const float* hs = hg + (size_t)p.x*80;
        #pragma unroll
        for (int j = 0; j < 5; ++j) acc[j] = fmaf(ex, hs[l + 16*j], acc[j]);
    }
    float inv = 1.f/denom;
    #pragma unroll
    for (int j = 0; j < 5; ++j) {
        int ch = l + 16*j;
        float v = acc[j]*inv + gat_b[ch];
        hgbn[(size_t)n*80 + ch] = consts[CO_BN1S + ch]*v + consts[CO_BN1SH + ch];
    }
}

// ---------------- mamba: depthwise conv + silu, x_proj, dt ----------------
__global__ __launch_bounds__(256) void k_conv_proj(const float* __restrict__ xc,
        const float* __restrict__ conv_w, const float* __restrict__ conv_b,
        const float* __restrict__ xp_W, const float* __restrict__ dt_W,
        const float* __restrict__ dt_b, float* __restrict__ u_g,
        float* __restrict__ Bm, float* __restrict__ Cm, float* __restrict__ dt_g)
{
    __shared__ float us[40][80];
    __shared__ float dtr[40][5];
    int g = blockIdx.x / 25, chunk = blockIdx.x % 25;
    int t0 = chunk * 40;
    int tid = threadIdx.x;
    size_t gbase = (size_t)g * NPG;
    for (int idx = tid; idx < 40*80; idx += 256) {
        int t = idx / 80, d = idx - t*80;
        int tt = t0 + t;
        float acc = conv_b[d];
        #pragma unroll
        for (int k = 0; k < 4; ++k) {
            int ti = tt - 3 + k;
            float xv = (ti >= 0) ? xc[(gbase + ti)*80 + d] : 0.f;
            acc = fmaf(xv, conv_w[d*4 + k], acc);
        }
        float uv = siluf(acc);
        us[t][d] = uv;
        u_g[(gbase + tt)*80 + d] = uv;
    }
    __syncthreads();
    for (int idx = tid; idx < 40*37; idx += 256) {
        int t = idx / 37, j = idx - t*37;
        float acc = 0.f;
        #pragma unroll 4
        for (int k = 0; k < 80; ++k) acc = fmaf(us[t][k], xp_W[k*37 + j], acc);
        int tt = t0 + t;
        if (j < 5) dtr[t][j] = acc;
        else if (j < 21) Bm[(gbase + tt)*16 + (j-5)] = acc;
        else Cm[(gbase + tt)*16 + (j-21)] = acc;
    }
    __syncthreads();
    for (int idx = tid; idx < 40*80; idx += 256) {
        int t = idx / 80, d = idx - t*80;
        float acc = dt_b[d];
        #pragma unroll
        for (int r = 0; r < 5; ++r) acc = fmaf(dtr[t][r], dt_W[r*80 + d], acc);
        float sp = (acc > 20.f) ? acc : log1pf(__expf(acc));
        dt_g[(gbase + t0 + t)*80 + d] = sp;
    }
}

// ---------------- SSM chunked scan, phase A: per-chunk (P = prod dA, Q = h_end|h0=0) ----------------
__global__ __launch_bounds__(256) void k_scan_a(const float* __restrict__ dt,
        const float* __restrict__ u, const float* __restrict__ Bm,
        const float* __restrict__ A_log, float* __restrict__ Pb, float* __restrict__ Qb)
{
    int b = blockIdx.x;               // b = (g*5 + dblk)*NCHUNK + c
    int c = b % NCHUNK; int gd = b / NCHUNK;
    int g = gd / 5, dblk = gd % 5;
    int dl = threadIdx.x >> 4, s = threadIdx.x & 15;
    int d = dblk*16 + dl;
    float a = -__expf(A_log[d*16 + s]);
    size_t base80 = (size_t)g*NPG*80 + (size_t)c*CLEN*80 + d;
    size_t base16 = (size_t)g*NPG*16 + (size_t)c*CLEN*16 + s;
    float P = 1.f, Q = 0.f;
    for (int t = 0; t < CLEN; ++t) {
        float dtv = dt[base80 + (size_t)t*80];
        float uv  = u [base80 + (size_t)t*80];
        float Bv  = Bm[base16 + (size_t)t*16];
        float dA = __expf(dtv * a);
        Q = fmaf(dA, Q, dtv*uv*Bv);
        P *= dA;
    }
    size_t o = ((size_t)(g*NCHUNK + c)*80 + d)*16 + s;
    Pb[o] = P; Qb[o] = Q;
}

// ---------------- SSM chunked scan, phase C: combine h_start, emit y ----------------
__global__ __launch_bounds__(256) void k_scan_c(const float* __restrict__ dt,
        const float* __restrict__ u, const float* __restrict__ Bm,
        const float* __restrict__ Cm, const float* __restrict__ A_log,
        const float* __restrict__ Dp, const float* __restrict__ sz,
        const float* __restrict__ Pb, const float* __restrict__ Qb,
        float* __restrict__ yraw)
{
    int b = blockIdx.x;
    int c = b % NCHUNK; int gd = b / NCHUNK;
    int g = gd / 5, dblk = gd % 5;
    int dl = threadIdx.x >> 4, s = threadIdx.x & 15;
    int d = dblk*16 + dl;
    float a = -__expf(A_log[d*16 + s]);
    float Dd = Dp[d];
    // combine starting state from earlier chunks (L2-resident, <=9 iters)
    float hst = 0.f;
    for (int cc = 0; cc < c; ++cc) {
        size_t o = ((size_t)(g*NCHUNK + cc)*80 + d)*16 + s;
        hst = fmaf(Pb[o], hst, Qb[o]);
    }
    size_t base80 = (size_t)g*NPG*80 + (size_t)c*CLEN*80 + d;
    size_t base16 = (size_t)g*NPG*16 + (size_t)c*CLEN*16 + s;
    for (int t = 0; t < CLEN; ++t) {
        float dtv = dt[base80 + (size_t)t*80];
        float uv  = u [base80 + (size_t)t*80];
        float Bv  = Bm[base16 + (size_t)t*16];
        float Cv  = Cm[base16 + (size_t)t*16];
        float dA = __expf(dtv * a);
        hst = fmaf(dA, hst, dtv*uv*Bv);
        float cv = hst * Cv;
        cv += __shfl_xor(cv, 1, 16);
        cv += __shfl_xor(cv, 2, 16);
        cv += __shfl_xor(cv, 4, 16);
        cv += __shfl_xor(cv, 8, 16);
        if (s == 0) {
            size_t i = base80 + (size_t)t*80;
            yraw[i] = (cv + uv*Dd) * sz[i];
        }
    }
}

// ---------------- per-graph mean pool (direct write, no atomics) ----------------
__global__ __launch_bounds__(320) void k_pool(const float* __restrict__ s2,
        float* __restrict__ pooled)
{
    __shared__ float part[4][80];
    int g = blockIdx.x;
    int tid = threadIdx.x;
    int c = tid % 80, rg = tid / 80;
    float sum = 0.f;
    const float* base = s2 + (size_t)g*NPG*80;
    for (int r = rg; r < NPG; r += 4)
        sum += base[(size_t)r*80 + c];
    part[rg][c] = sum;
    __syncthreads();
    if (tid < 80)
        pooled[g*80 + tid] = part[0][tid] + part[1][tid] + part[2][tid] + part[3][tid];
}

// ---------------- pooled mean + final 3-layer MLP ----------------
__global__ __launch_bounds__(256) void k_pool_final(const float* __restrict__ pooled,
        const float* __restrict__ f_W1, const float* __restrict__ f_b1,
        const float* __restrict__ f_W2, const float* __restrict__ f_b2,
        const float* __restrict__ f_W3, const float* __restrict__ f_b3,
        float* __restrict__ d_out)
{
    __shared__ float pl[50*80];
    __shared__ float h1[50*40];
    __shared__ float h2[50*20];
    int tid = threadIdx.x;
    for (int idx = tid; idx < 50*80; idx += 256) {
        float v = pooled[idx] * (1.f/NPG);
        pl[idx] = v;
        d_out[50 + idx] = v;
    }
    __syncthreads();
    for (int idx = tid; idx < 50*40; idx += 256) {
        int g = idx / 40, j = idx - g*40;
        float acc = f_b1[j];
        for (int k = 0; k < 80; ++k) acc = fmaf(pl[g*80+k], f_W1[k*40+j], acc);
        h1[idx] = fmaxf(acc, 0.f);
    }
    __syncthreads();
    for (int idx = tid; idx < 50*20; idx += 256) {
        int g = idx / 20, j = idx - g*20;
        float acc = f_b2[j];
        for (int k = 0; k < 40; ++k) acc = fmaf(h1[g*40+k], f_W2[k*20+j], acc);
        h2[idx] = fmaxf(acc, 0.f);
    }
    __syncthreads();
    if (tid < 50) {
        float acc = f_b3[0];
        for (int k = 0; k < 20; ++k) acc = fmaf(h2[tid*20+k], f_W3[k], acc);
        d_out[tid] = acc;
    }
}

extern "C" void kernel_launch(void* const* d_in, const int* in_sizes, int n_in,
                              void* d_out, int out_size, void* d_ws, size_t ws_size,
                              hipStream_t stream)
{
    (void)in_sizes; (void)n_in; (void)out_size; (void)ws_size;
    const float* x        = (const float*)d_in[0];
    const int*   eidx     = (const int*)d_in[1];
    const int*   ea_cat   = (const int*)d_in[2];
    const float* ea_cont  = (const float*)d_in[3];
    const float* W_uni    = (const float*)d_in[4];
    const float* b_uni    = (const float*)d_in[5];
    const float* edge_emb = (const float*)d_in[6];
    const float* W_edge   = (const float*)d_in[7];
    const float* b_edge   = (const float*)d_in[8];
    const float* gat_W    = (const float*)d_in[9];
    const float* gat_as   = (const float*)d_in[10];
    const float* gat_ad   = (const float*)d_in[11];
    const float* gat_We   = (const float*)d_in[12];
    const float* gat_ae   = (const float*)d_in[13];
    const float* gat_b    = (const float*)d_in[14];
    const float* bn1_w = (const float*)d_in[15]; const float* bn1_b = (const float*)d_in[16];
    const float* bn1_m = (const float*)d_in[17]; const float* bn1_v = (const float*)d_in[18];
    const float* bn2_w = (const float*)d_in[19]; const float* bn2_b = (const float*)d_in[20];
    const float* bn2_m = (const float*)d_in[21]; const float* bn2_v = (const float*)d_in[22];
    const float* bn3_w = (const float*)d_in[23]; const float* bn3_b = (const float*)d_in[24];
    const float* bn3_m = (const float*)d_in[25]; const float* bn3_v = (const float*)d_in[26];
    const float* m_in_W   = (const float*)d_in[27];
    const float* m_conv_w = (const float*)d_in[28];
    const float* m_conv_b = (const float*)d_in[29];
    const float* m_xp_W   = (const float*)d_in[30];
    const float* m_dt_W   = (const float*)d_in[31];
    const float* m_dt_b   = (const float*)d_in[32];
    const float* m_Alog   = (const float*)d_in[33];
    const float* m_D      = (const float*)d_in[34];
    const float* m_out_W  = (const float*)d_in[35];
    const float* mlp_W1 = (const float*)d_in[36]; const float* mlp_b1 = (const float*)d_in[37];
    const float* mlp_W2 = (const float*)d_in[38]; const float* mlp_b2 = (const float*)d_in[39];
    const float* f_W1 = (const float*)d_in[40]; const float* f_b1 = (const float*)d_in[41];
    const float* f_W2 = (const float*)d_in[42]; const float* f_b2 = (const float*)d_in[43];
    const float* f_W3 = (const float*)d_in[44]; const float* f_b3 = (const float*)d_in[45];

    const int* src = eidx;
    const int* dst = eidx + NEDGES;

    float* wsf = (float*)d_ws;
    const size_t NN80 = (size_t)NNODES*80;
    size_t O_CONSTS = 0;
    size_t O_SUMAE  = 1024;
    size_t O_CNT    = O_SUMAE + NNODES;          // int
    size_t O_POOLED = O_CNT + NNODES;
    size_t O_AE     = O_POOLED + 4000;
    size_t O_AS     = O_AE + NEDGES;
    size_t O_AD     = O_AS + NNODES;
    size_t O_ASELF  = O_AD + NNODES;
    size_t O_ROWPTR = O_ASELF + NNODES;          // int
    size_t O_CURSOR = O_ROWPTR + NNODES;         // int
    size_t O_BSUM   = O_CURSOR + NNODES;         // int, 256
    size_t O_EBUF   = O_BSUM + 256;              // int2 x NEDGES (8B aligned); dead after k_gat_agg
    size_t O_PB     = O_EBUF;                    // reuse: 640000 floats
    size_t O_QB     = O_EBUF + 640000;           // reuse: 640000 floats
    size_t O_H      = O_EBUF + 2*(size_t)NEDGES; // h, later s1
    size_t O_HG     = O_H + NN80;                // hg, later yraw
    size_t O_HGBN   = O_HG + NN80;               // hgbn; later t1 (spans HGBN+XC, 8M floats)
    size_t O_XC     = O_HGBN + NN80;
    size_t O_SZ     = O_XC + NN80;               // sz; later s2
    size_t O_U      = O_SZ + NN80;
    size_t O_DT     = O_U + NN80;
    size_t O_BM     = O_DT + NN80;
    size_t O_CM     = O_BM + (size_t)NNODES*16;
    size_t O_T1     = O_HGBN;                    // reuse: 50000x160 (dead after out_W GEMM)
    size_t O_S2     = O_SZ;                      // reuse: 50000x80 (dead after scan_c)

    // zero: sum_ae, cnt (contiguous)
    hipMemsetAsync(wsf + O_SUMAE, 0, 2*(size_t)NNODES*sizeof(float), stream);

    k_precompute<<<1, 256, 0, stream>>>(gat_W, gat_as, gat_ad, gat_We, gat_ae,
        W_edge, b_edge, edge_emb,
        bn1_w, bn1_b, bn1_m, bn1_v, bn2_w, bn2_b, bn2_m, bn2_v, bn3_w, bn3_b, bn3_m, bn3_v,
        wsf + O_CONSTS);

    k_feat<<<(NNODES + 63)/64, 256, 0, stream>>>(x, W_uni, b_uni, wsf + O_H);

    k_edge_scalar<<<(NEDGES + 255)/256, 256, 0, stream>>>(ea_cont, ea_cat, dst,
        wsf + O_CONSTS, wsf + O_AE, wsf + O_SUMAE, (int*)(wsf + O_CNT));

    k_gemm_rows<80, 80, 8, 0><<<(NNODES + 31)/32, 320, 0, stream>>>(
        wsf + O_H, gat_W, wsf + O_HG, nullptr, nullptr, nullptr, wsf + O_CONSTS, NNODES);

    k_node_as<<<(NNODES + 255)/256, 256, 0, stream>>>(wsf + O_H, wsf + O_CONSTS,
        wsf + O_SUMAE, (const int*)(wsf + O_CNT), wsf + O_AS, wsf + O_AD, wsf + O_ASELF);

    k_psum1<<<NB_SCAN, 256, 0, stream>>>((const int*)(wsf + O_CNT), (int*)(wsf + O_BSUM));
    k_psum2<<<1, 256, 0, stream>>>((int*)(wsf + O_BSUM));
    k_psum3<<<NB_SCAN, 256, 0, stream>>>((const int*)(wsf + O_CNT),
        (const int*)(wsf + O_BSUM), (int*)(wsf + O_ROWPTR), (int*)(wsf + O_CURSOR));

    k_bucket<<<(NEDGES + 255)/256, 256, 0, stream>>>(src, dst, wsf + O_AS,
        wsf + O_AD, wsf + O_AE, (int*)(wsf + O_CURSOR), (int2*)(wsf + O_EBUF));

    k_gat_agg<<<NNODES/16, 256, 0, stream>>>((const int*)(wsf + O_ROWPTR),
        (const int*)(wsf + O_CNT), (const int2*)(wsf + O_EBUF), wsf + O_ASELF,
        wsf + O_HG, gat_b, wsf + O_CONSTS, wsf + O_HGBN);

    k_gemm_rows<80, 160, 8, 1><<<(NNODES + 15)/16, 320, 0, stream>>>(
        wsf + O_H, m_in_W, wsf + O_XC, wsf + O_SZ, nullptr, nullptr, wsf + O_CONSTS, NNODES);

    k_conv_proj<<<NGRAPHS*25, 256, 0, stream>>>(wsf + O_XC, m_conv_w, m_conv_b,
        m_xp_W, m_dt_W, m_dt_b, wsf + O_U, wsf + O_BM, wsf + O_CM, wsf + O_DT);

    // chunked SSM scan (ebuf region reused for P/Q — dead after k_gat_agg)
    k_scan_a<<<NGRAPHS*5*NCHUNK, 256, 0, stream>>>(wsf + O_DT, wsf + O_U,
        wsf + O_BM, m_Alog, wsf + O_PB, wsf + O_QB);

    k_scan_c<<<NGRAPHS*5*NCHUNK, 256, 0, stream>>>(wsf + O_DT, wsf + O_U,
        wsf + O_BM, wsf + O_CM, m_Alog, m_D, wsf + O_SZ,
        wsf + O_PB, wsf + O_QB, wsf + O_HG /*yraw*/);

    k_gemm_rows<80, 80, 8, 2><<<(NNODES + 31)/32, 320, 0, stream>>>(
        wsf + O_HG /*yraw*/, m_out_W, wsf + O_H /*s1*/, nullptr,
        wsf + O_HGBN, nullptr, wsf + O_CONSTS, NNODES);

    // residual MLP: s1 -> t1 (relu) -> s2 (residual+bn3+relu)
    k_gemm_rows<80, 160, 8, 3><<<(NNODES + 15)/16, 320, 0, stream>>>(
        wsf + O_H /*s1*/, mlp_W1, wsf + O_T1, nullptr, nullptr, mlp_b1,
        wsf + O_CONSTS, NNODES);

    k_gemm_rows<160, 80, 8, 4><<<(NNODES + 31)/32, 320, 0, stream>>>(
        wsf + O_T1, mlp_W2, wsf + O_S2, nullptr, wsf + O_H /*s1 residual*/, mlp_b2,
        wsf + O_CONSTS, NNODES);

    k_pool<<<NGRAPHS, 320, 0, stream>>>(wsf + O_S2, wsf + O_POOLED);

    k_pool_final<<<1, 256, 0, stream>>>(wsf + O_POOLED, f_W1, f_b1, f_W2, f_b2,
        f_W3, f_b3, (float*)d_out);
}